// Round 8
// baseline (438.574 us; speedup 1.0000x reference)
//
#include <hip/hip_runtime.h>

// NConv depth-completion net, fp32. R8 = R7 + 2x2 px/thread (32x32 tiles) for
// nconv5p4 / nconv3cat / nconv3p: kj-outer loop loads each weight pack once
// per 4 px (was once per 2), staging/barrier/epilogue amortized 2x. Parity
// LDS (8B-stride taps, conflict-free) kept. unroll 1 on ci kept (R4: full
// unroll -> 256 VGPR spill). No minwaves (R2). Packed-global float4 kept.

#define EPSN 1e-20f

typedef float v2f __attribute__((ext_vector_type(2)));

__device__ __forceinline__ float softplusf(float x) {
    return fmaxf(x, 0.f) + log1pf(expf(-fabsf(x)));
}
__device__ __forceinline__ float rcpf(float x) { return __builtin_amdgcn_rcpf(x); }

// Sum s_w4[0..n) across wave 0; lane 0 writes *dst. Needs __syncthreads after.
__device__ __forceinline__ void wsum4(const float4* s_w4, int n, int tid, float4* dst)
{
    if (tid < 64) {
        float4 a = make_float4(0.f, 0.f, 0.f, 0.f);
        for (int i = tid; i < n; i += 64) {
            float4 w = s_w4[i];
            a.x += w.x; a.y += w.y; a.z += w.z; a.w += w.w;
        }
        #pragma unroll
        for (int off = 32; off; off >>= 1) {
            a.x += __shfl_xor(a.x, off);
            a.y += __shfl_xor(a.y, off);
            a.z += __shfl_xor(a.z, off);
            a.w += __shfl_xor(a.w, off);
        }
        if (tid == 0) *dst = a;
    }
}

// acc[co] {den,nom} += {w_co,w_co} * v {c,xc}
__device__ __forceinline__ void tap4(v2f v, float4 w, v2f* a)
{
    a[0] = __builtin_elementwise_fma((v2f){w.x, w.x}, v, a[0]);
    a[1] = __builtin_elementwise_fma((v2f){w.y, w.y}, v, a[1]);
    a[2] = __builtin_elementwise_fma((v2f){w.z, w.z}, v, a[2]);
    a[3] = __builtin_elementwise_fma((v2f){w.w, w.w}, v, a[3]);
}

// Store one pixel-pair row from acc sets aa (col ow) / ab (col ow+1).
__device__ __forceinline__ void store_row(
    float4* __restrict__ xout4, float4* __restrict__ cout4, size_t t,
    const v2f* aa, const v2f* ab, float4 bias,
    float rs0, float rs1, float rs2, float rs3, bool two)
{
    float4 xo, co;
    xo.x = aa[0].y * rcpf(aa[0].x + EPSN) + bias.x; co.x = aa[0].x * rs0;
    xo.y = aa[1].y * rcpf(aa[1].x + EPSN) + bias.y; co.y = aa[1].x * rs1;
    xo.z = aa[2].y * rcpf(aa[2].x + EPSN) + bias.z; co.z = aa[2].x * rs2;
    xo.w = aa[3].y * rcpf(aa[3].x + EPSN) + bias.w; co.w = aa[3].x * rs3;
    xout4[t] = xo; cout4[t] = co;
    if (two) {
        xo.x = ab[0].y * rcpf(ab[0].x + EPSN) + bias.x; co.x = ab[0].x * rs0;
        xo.y = ab[1].y * rcpf(ab[1].x + EPSN) + bias.y; co.y = ab[1].x * rs1;
        xo.z = ab[2].y * rcpf(ab[2].x + EPSN) + bias.z; co.z = ab[2].x * rs2;
        xo.w = ab[3].y * rcpf(ab[3].x + EPSN) + bias.w; co.w = ab[3].x * rs3;
        xout4[t + 1] = xo; cout4[t + 1] = co;
    }
}

// 2x2-px epilogue
#define NC_STORE22(HOUT, WOUT)                                              \
    {                                                                       \
        const int oh = oh0 + 2 * ty, ow = ow0 + 2 * tx;                     \
        if (ow < (WOUT)) {                                                  \
            float4 bias = s_bias, ssum = s_sum;                             \
            float rs0=rcpf(ssum.x), rs1=rcpf(ssum.y),                       \
                  rs2=rcpf(ssum.z), rs3=rcpf(ssum.w);                       \
            bool two = (ow + 1 < (WOUT));                                   \
            if (oh < (HOUT))                                                \
                store_row(xout4, cout4, ((size_t)b*(HOUT)+oh)*(WOUT)+ow,    \
                          aA0, aB0, bias, rs0, rs1, rs2, rs3, two);         \
            if (oh + 1 < (HOUT))                                            \
                store_row(xout4, cout4, ((size_t)b*(HOUT)+oh+1)*(WOUT)+ow,  \
                          aA1, aB1, bias, rs0, rs1, rs2, rs3, two);         \
        }                                                                   \
    }

// ---------------------------------------------------------------------------
// First 5x5 nconv: planar S in (c0 = S>0.01 on the fly), packed out.
// 32x16 tile, 2 px/thread (cheap layer, unchanged from R6/R7 structure).
// ---------------------------------------------------------------------------
__global__ __launch_bounds__(256) void nconv5_first(
    const float* __restrict__ S,
    const float* __restrict__ wraw, const float* __restrict__ braw,
    float4* __restrict__ xout4, float4* __restrict__ cout4,
    int Hh, int Ww)
{
    __shared__ v2f sdE[20][19], sdO[20][19];
    __shared__ float4 s_w4[25];
    __shared__ float4 s_sum, s_bias;
    const int b = blockIdx.z;
    const int oh0 = blockIdx.y * 16, ow0 = blockIdx.x * 32;
    const int tx = threadIdx.x, ty = threadIdx.y, tid = ty * 16 + tx;

    if (tid < 25) {
        float4 w;
        w.x = softplusf(wraw[tid]);      w.y = softplusf(wraw[25 + tid]);
        w.z = softplusf(wraw[50 + tid]); w.w = softplusf(wraw[75 + tid]);
        s_w4[tid] = w;
    }
    if (tid == 0) s_bias = make_float4(braw[0], braw[1], braw[2], braw[3]);
    __syncthreads();

    for (int i = tid; i < 20 * 18; i += 256) {
        int ly = i / 18, j = i - ly * 18;
        int ih = oh0 - 2 + ly, iw = ow0 - 2 + 2 * j;
        float s0 = 0.f, s1 = 0.f;
        if ((unsigned)ih < (unsigned)Hh && iw >= 0 && iw < Ww - 1) {
            float2 t = *(const float2*)&S[((size_t)b * Hh + ih) * Ww + iw];
            s0 = t.x; s1 = t.y;
        }
        float c0 = (s0 > 0.01f) ? 1.f : 0.f;
        float c1 = (s1 > 0.01f) ? 1.f : 0.f;
        sdE[ly][j] = (v2f){c0, s0 * c0};
        sdO[ly][j] = (v2f){c1, s1 * c1};
    }
    wsum4(s_w4, 25, tid, &s_sum);
    __syncthreads();

    v2f aA0[4] = {}, aB0[4] = {};
    #pragma unroll
    for (int kj = 0; kj < 5; ++kj) {
        const v2f* rE = &sdE[ty + kj][tx];
        const v2f* rO = &sdO[ty + kj][tx];
        v2f e0 = rE[0], o0 = rO[0], e1 = rE[1], o1 = rO[1], e2 = rE[2], o2 = rO[2];
        const float4* wr = &s_w4[kj * 5];
        float4 w;
        w = wr[0]; tap4(e0, w, aA0); tap4(o0, w, aB0);
        w = wr[1]; tap4(o0, w, aA0); tap4(e1, w, aB0);
        w = wr[2]; tap4(e1, w, aA0); tap4(o1, w, aB0);
        w = wr[3]; tap4(o1, w, aA0); tap4(e2, w, aB0);
        w = wr[4]; tap4(e2, w, aA0); tap4(o2, w, aB0);
    }
    {
        const int oh = oh0 + ty, ow = ow0 + 2 * tx;
        if (oh < Hh && ow < Ww) {
            float4 bias = s_bias, ssum = s_sum;
            float rs0 = rcpf(ssum.x), rs1 = rcpf(ssum.y),
                  rs2 = rcpf(ssum.z), rs3 = rcpf(ssum.w);
            store_row(xout4, cout4, ((size_t)b * Hh + oh) * Ww + ow,
                      aA0, aB0, bias, rs0, rs1, rs2, rs3, ow + 1 < Ww);
        }
    }
}

// ---------------------------------------------------------------------------
// 5x5 nconv, CI=4, packed in/out. 32x32 tile, 2x2 px/thread, parity LDS.
// ---------------------------------------------------------------------------
__global__ __launch_bounds__(256) void nconv5p4(
    const float4* __restrict__ xin4, const float4* __restrict__ cin4,
    const float* __restrict__ wraw, const float* __restrict__ braw,
    float4* __restrict__ xout4, float4* __restrict__ cout4,
    int Hh, int Ww)
{
    __shared__ v2f sdE[4][36][19], sdO[4][36][19];   // 32+4 rows, 18 col-pairs
    __shared__ float4 s_w4[100];
    __shared__ float4 s_sum, s_bias;
    const int b = blockIdx.z;
    const int oh0 = blockIdx.y * 32, ow0 = blockIdx.x * 32;
    const int tx = threadIdx.x, ty = threadIdx.y, tid = ty * 16 + tx;

    if (tid < 100) {
        float4 w;
        w.x = softplusf(wraw[tid]);       w.y = softplusf(wraw[100 + tid]);
        w.z = softplusf(wraw[200 + tid]); w.w = softplusf(wraw[300 + tid]);
        s_w4[tid] = w;
    }
    if (tid == 0) s_bias = make_float4(braw[0], braw[1], braw[2], braw[3]);
    __syncthreads();

    const float4 z = make_float4(0.f, 0.f, 0.f, 0.f);
    for (int i = tid; i < 36 * 18; i += 256) {
        int ly = i / 18, j = i - ly * 18;
        int ih = oh0 - 2 + ly, iw = ow0 - 2 + 2 * j;
        float4 cA = z, xA = z, cB = z, xB = z;
        if ((unsigned)ih < (unsigned)Hh) {
            size_t rb = ((size_t)b * Hh + ih) * Ww;
            if ((unsigned)iw < (unsigned)Ww)       { cA = cin4[rb + iw];     xA = xin4[rb + iw]; }
            if ((unsigned)(iw + 1) < (unsigned)Ww) { cB = cin4[rb + iw + 1]; xB = xin4[rb + iw + 1]; }
        }
        sdE[0][ly][j] = (v2f){cA.x, xA.x * cA.x};
        sdE[1][ly][j] = (v2f){cA.y, xA.y * cA.y};
        sdE[2][ly][j] = (v2f){cA.z, xA.z * cA.z};
        sdE[3][ly][j] = (v2f){cA.w, xA.w * cA.w};
        sdO[0][ly][j] = (v2f){cB.x, xB.x * cB.x};
        sdO[1][ly][j] = (v2f){cB.y, xB.y * cB.y};
        sdO[2][ly][j] = (v2f){cB.z, xB.z * cB.z};
        sdO[3][ly][j] = (v2f){cB.w, xB.w * cB.w};
    }
    wsum4(s_w4, 100, tid, &s_sum);
    __syncthreads();

    v2f aA0[4] = {}, aB0[4] = {}, aA1[4] = {}, aB1[4] = {};
    #pragma unroll 1
    for (int ci = 0; ci < 4; ++ci) {
        #pragma unroll
        for (int kj = 0; kj < 5; ++kj) {
            const float4* wr = &s_w4[ci * 25 + kj * 5];
            float4 w0 = wr[0], w1 = wr[1], w2 = wr[2], w3 = wr[3], w4 = wr[4];
            {   // output row 0: input row 2ty+kj
                const v2f* rE = &sdE[ci][2 * ty + kj][tx];
                const v2f* rO = &sdO[ci][2 * ty + kj][tx];
                v2f e0 = rE[0], o0 = rO[0], e1 = rE[1], o1 = rO[1], e2 = rE[2], o2 = rO[2];
                tap4(e0, w0, aA0); tap4(o0, w0, aB0);
                tap4(o0, w1, aA0); tap4(e1, w1, aB0);
                tap4(e1, w2, aA0); tap4(o1, w2, aB0);
                tap4(o1, w3, aA0); tap4(e2, w3, aB0);
                tap4(e2, w4, aA0); tap4(o2, w4, aB0);
            }
            {   // output row 1: input row 2ty+1+kj
                const v2f* rE = &sdE[ci][2 * ty + 1 + kj][tx];
                const v2f* rO = &sdO[ci][2 * ty + 1 + kj][tx];
                v2f e0 = rE[0], o0 = rO[0], e1 = rE[1], o1 = rO[1], e2 = rE[2], o2 = rO[2];
                tap4(e0, w0, aA1); tap4(o0, w0, aB1);
                tap4(o0, w1, aA1); tap4(e1, w1, aB1);
                tap4(e1, w2, aA1); tap4(o1, w2, aB1);
                tap4(o1, w3, aA1); tap4(e2, w3, aB1);
                tap4(e2, w4, aA1); tap4(o2, w4, aB1);
            }
        }
    }
    NC_STORE22(Hh, Ww)
}

// ---------------------------------------------------------------------------
// 2x2 argmax-of-confidence pool, packed: all 4 channels per thread.
// ---------------------------------------------------------------------------
__global__ __launch_bounds__(256) void pool2k(
    const float4* __restrict__ x4, const float4* __restrict__ c4,
    float4* __restrict__ xo4, float4* __restrict__ co4, int Hh, int Ww)
{
    int H2 = Hh / 2, W2 = Ww / 2;
    int total = 8 * H2 * W2;
    int i = blockIdx.x * 256 + threadIdx.x;
    if (i >= total) return;
    int ow = i % W2;
    int oh = (i / W2) % H2;
    int b  = i / (W2 * H2);
    size_t r0 = ((size_t)b * Hh + 2 * oh) * Ww + 2 * ow;
    size_t r1 = r0 + Ww;
    float4 c00 = c4[r0], c01 = c4[r0 + 1], c10 = c4[r1], c11 = c4[r1 + 1];
    float4 x00 = x4[r0], x01 = x4[r0 + 1], x10 = x4[r1], x11 = x4[r1 + 1];
    float4 cm, xm;
    cm.x = c00.x; xm.x = x00.x;
    if (c01.x > cm.x) { cm.x = c01.x; xm.x = x01.x; }
    if (c10.x > cm.x) { cm.x = c10.x; xm.x = x10.x; }
    if (c11.x > cm.x) { cm.x = c11.x; xm.x = x11.x; }
    cm.y = c00.y; xm.y = x00.y;
    if (c01.y > cm.y) { cm.y = c01.y; xm.y = x01.y; }
    if (c10.y > cm.y) { cm.y = c10.y; xm.y = x10.y; }
    if (c11.y > cm.y) { cm.y = c11.y; xm.y = x11.y; }
    cm.z = c00.z; xm.z = x00.z;
    if (c01.z > cm.z) { cm.z = c01.z; xm.z = x01.z; }
    if (c10.z > cm.z) { cm.z = c10.z; xm.z = x10.z; }
    if (c11.z > cm.z) { cm.z = c11.z; xm.z = x11.z; }
    cm.w = c00.w; xm.w = x00.w;
    if (c01.w > cm.w) { cm.w = c01.w; xm.w = x01.w; }
    if (c10.w > cm.w) { cm.w = c10.w; xm.w = x10.w; }
    if (c11.w > cm.w) { cm.w = c11.w; xm.w = x11.w; }
    size_t o = ((size_t)b * H2 + oh) * W2 + ow;
    xo4[o] = xm;
    cm.x *= 0.25f; cm.y *= 0.25f; cm.z *= 0.25f; cm.w *= 0.25f;
    co4[o] = cm;
}

// ---------------------------------------------------------------------------
// 3x3 nconv over concat{direct 4ch (Hin,Win), nearest-2x-up 4ch (Hin/2,Win/2)}.
// Up staged at native half-res. 32x32 tile, 2x2 px/thread, parity LDS (direct).
// UP_FIRST: up occupies weight channels 0-3 (w6) else 4-7 (w4,w5).
// ---------------------------------------------------------------------------
template<bool UP_FIRST, int PAD>
__global__ __launch_bounds__(256) void nconv3cat(
    const float4* __restrict__ xd4, const float4* __restrict__ cd4,
    const float4* __restrict__ xu4, const float4* __restrict__ cu4,
    const float* __restrict__ wraw, const float* __restrict__ braw,
    float4* __restrict__ xout4, float4* __restrict__ cout4,
    int Hin, int Win)
{
    __shared__ v2f sdE[4][34][18], sdO[4][34][18];   // 32+2 rows, 17 col-pairs
    __shared__ v2f sup[4][18][19];                   // up, native half-res
    __shared__ float4 s_w4[72];
    __shared__ float4 s_sum, s_bias;

    const int Hout = Hin - 2 + 2 * PAD, Wout = Win - 2 + 2 * PAD;
    const int Hu = Hin / 2, Wu = Win / 2;
    const int b = blockIdx.z;
    const int oh0 = blockIdx.y * 32, ow0 = blockIdx.x * 32;
    const int tx = threadIdx.x, ty = threadIdx.y, tid = ty * 16 + tx;

    if (tid < 72) {
        float4 w;
        w.x = softplusf(wraw[tid]);       w.y = softplusf(wraw[72 + tid]);
        w.z = softplusf(wraw[144 + tid]); w.w = softplusf(wraw[216 + tid]);
        s_w4[tid] = w;
    }
    if (tid == 0) s_bias = make_float4(braw[0], braw[1], braw[2], braw[3]);
    __syncthreads();

    const float4 z = make_float4(0.f, 0.f, 0.f, 0.f);
    for (int i = tid; i < 34 * 17; i += 256) {
        int ly = i / 17, j = i - ly * 17;
        int ih = oh0 - PAD + ly, iw = ow0 - PAD + 2 * j;
        float4 cA = z, xA = z, cB = z, xB = z;
        if ((unsigned)ih < (unsigned)Hin) {
            size_t rb = ((size_t)b * Hin + ih) * Win;
            if ((unsigned)iw < (unsigned)Win)       { cA = cd4[rb + iw];     xA = xd4[rb + iw]; }
            if ((unsigned)(iw + 1) < (unsigned)Win) { cB = cd4[rb + iw + 1]; xB = xd4[rb + iw + 1]; }
        }
        sdE[0][ly][j] = (v2f){cA.x, xA.x * cA.x};
        sdE[1][ly][j] = (v2f){cA.y, xA.y * cA.y};
        sdE[2][ly][j] = (v2f){cA.z, xA.z * cA.z};
        sdE[3][ly][j] = (v2f){cA.w, xA.w * cA.w};
        sdO[0][ly][j] = (v2f){cB.x, xB.x * cB.x};
        sdO[1][ly][j] = (v2f){cB.y, xB.y * cB.y};
        sdO[2][ly][j] = (v2f){cB.z, xB.z * cB.z};
        sdO[3][ly][j] = (v2f){cB.w, xB.w * cB.w};
    }
    const int ru0 = (oh0 - PAD) >> 1, cu0 = (ow0 - PAD) >> 1;
    for (int i = tid; i < 18 * 18; i += 256) {
        int r = i / 18, k = i - r * 18;
        int ur = ru0 + r, uc = cu0 + k;
        float4 cU = z, xU = z;
        if ((unsigned)ur < (unsigned)Hu && (unsigned)uc < (unsigned)Wu) {
            size_t t = ((size_t)b * Hu + ur) * Wu + uc;
            cU = cu4[t]; xU = xu4[t];
        }
        sup[0][r][k] = (v2f){cU.x, xU.x * cU.x};
        sup[1][r][k] = (v2f){cU.y, xU.y * cU.y};
        sup[2][r][k] = (v2f){cU.z, xU.z * cU.z};
        sup[3][r][k] = (v2f){cU.w, xU.w * cU.w};
    }
    wsum4(s_w4, 72, tid, &s_sum);
    __syncthreads();

    v2f aA0[4] = {}, aB0[4] = {}, aA1[4] = {}, aB1[4] = {};
    #pragma unroll 1
    for (int ci = 0; ci < 4; ++ci) {
        const int chD = UP_FIRST ? ci + 4 : ci;
        const int chU = UP_FIRST ? ci : ci + 4;
        #pragma unroll
        for (int kj = 0; kj < 3; ++kj) {
            const float4* wr = &s_w4[chD * 9 + kj * 3];
            float4 w0 = wr[0], w1 = wr[1], w2 = wr[2];
            {
                const v2f* rE = &sdE[ci][2 * ty + kj][tx];
                const v2f* rO = &sdO[ci][2 * ty + kj][tx];
                v2f e0 = rE[0], o0 = rO[0], e1 = rE[1], o1 = rO[1];
                tap4(e0, w0, aA0); tap4(o0, w0, aB0);
                tap4(o0, w1, aA0); tap4(e1, w1, aB0);
                tap4(e1, w2, aA0); tap4(o1, w2, aB0);
            }
            {
                const v2f* rE = &sdE[ci][2 * ty + 1 + kj][tx];
                const v2f* rO = &sdO[ci][2 * ty + 1 + kj][tx];
                v2f e0 = rE[0], o0 = rO[0], e1 = rE[1], o1 = rO[1];
                tap4(e0, w0, aA1); tap4(o0, w0, aB1);
                tap4(o0, w1, aA1); tap4(e1, w1, aB1);
                tap4(e1, w2, aA1); tap4(o1, w2, aB1);
            }
        }
        #pragma unroll
        for (int kj = 0; kj < 3; ++kj) {
            const float4* wr = &s_w4[chU * 9 + kj * 3];
            float4 w0 = wr[0], w1 = wr[1], w2 = wr[2];
            #pragma unroll
            for (int r = 0; r < 2; ++r) {
                v2f* a0 = r ? aA1 : aA0;
                v2f* a1 = r ? aB1 : aB0;
                int lyu = (2 * ty + r + kj + PAD) >> 1;
                const v2f* ru = &sup[ci][lyu][tx];
                v2f u0 = ru[0], u1 = ru[1];
                v2f q0, q1, q2, q3;
                if (PAD == 1) {
                    v2f u2 = ru[2];
                    q0 = u0; q1 = u1; q2 = u1; q3 = u2;   // idx = (m+1)>>1
                } else {
                    q0 = u0; q1 = u0; q2 = u1; q3 = u1;   // idx = m>>1
                }
                tap4(q0, w0, a0); tap4(q1, w0, a1);
                tap4(q1, w1, a0); tap4(q2, w1, a1);
                tap4(q2, w2, a0); tap4(q3, w2, a1);
            }
        }
    }
    NC_STORE22(Hout, Wout)
}

// ---------------------------------------------------------------------------
// 3x3 nconv, 4->4, pad=1 (w65), packed. 32x32 tile, 2x2 px/thread, parity LDS.
// ---------------------------------------------------------------------------
__global__ __launch_bounds__(256) void nconv3p(
    const float4* __restrict__ xin4, const float4* __restrict__ cin4,
    const float* __restrict__ wraw, const float* __restrict__ braw,
    float4* __restrict__ xout4, float4* __restrict__ cout4,
    int Hh, int Ww)
{
    __shared__ v2f sdE[4][34][18], sdO[4][34][18];
    __shared__ float4 s_w4[36];
    __shared__ float4 s_sum, s_bias;
    const int b = blockIdx.z;
    const int oh0 = blockIdx.y * 32, ow0 = blockIdx.x * 32;
    const int tx = threadIdx.x, ty = threadIdx.y, tid = ty * 16 + tx;

    if (tid < 36) {
        float4 w;
        w.x = softplusf(wraw[tid]);      w.y = softplusf(wraw[36 + tid]);
        w.z = softplusf(wraw[72 + tid]); w.w = softplusf(wraw[108 + tid]);
        s_w4[tid] = w;
    }
    if (tid == 0) s_bias = make_float4(braw[0], braw[1], braw[2], braw[3]);
    __syncthreads();

    const float4 z = make_float4(0.f, 0.f, 0.f, 0.f);
    for (int i = tid; i < 34 * 17; i += 256) {
        int ly = i / 17, j = i - ly * 17;
        int ih = oh0 - 1 + ly, iw = ow0 - 1 + 2 * j;
        float4 cA = z, xA = z, cB = z, xB = z;
        if ((unsigned)ih < (unsigned)Hh) {
            size_t rb = ((size_t)b * Hh + ih) * Ww;
            if ((unsigned)iw < (unsigned)Ww)       { cA = cin4[rb + iw];     xA = xin4[rb + iw]; }
            if ((unsigned)(iw + 1) < (unsigned)Ww) { cB = cin4[rb + iw + 1]; xB = xin4[rb + iw + 1]; }
        }
        sdE[0][ly][j] = (v2f){cA.x, xA.x * cA.x};
        sdE[1][ly][j] = (v2f){cA.y, xA.y * cA.y};
        sdE[2][ly][j] = (v2f){cA.z, xA.z * cA.z};
        sdE[3][ly][j] = (v2f){cA.w, xA.w * cA.w};
        sdO[0][ly][j] = (v2f){cB.x, xB.x * cB.x};
        sdO[1][ly][j] = (v2f){cB.y, xB.y * cB.y};
        sdO[2][ly][j] = (v2f){cB.z, xB.z * cB.z};
        sdO[3][ly][j] = (v2f){cB.w, xB.w * cB.w};
    }
    wsum4(s_w4, 36, tid, &s_sum);
    __syncthreads();

    v2f aA0[4] = {}, aB0[4] = {}, aA1[4] = {}, aB1[4] = {};
    #pragma unroll 1
    for (int ci = 0; ci < 4; ++ci) {
        #pragma unroll
        for (int kj = 0; kj < 3; ++kj) {
            const float4* wr = &s_w4[ci * 9 + kj * 3];
            float4 w0 = wr[0], w1 = wr[1], w2 = wr[2];
            {
                const v2f* rE = &sdE[ci][2 * ty + kj][tx];
                const v2f* rO = &sdO[ci][2 * ty + kj][tx];
                v2f e0 = rE[0], o0 = rO[0], e1 = rE[1], o1 = rO[1];
                tap4(e0, w0, aA0); tap4(o0, w0, aB0);
                tap4(o0, w1, aA0); tap4(e1, w1, aB0);
                tap4(e1, w2, aA0); tap4(o1, w2, aB0);
            }
            {
                const v2f* rE = &sdE[ci][2 * ty + 1 + kj][tx];
                const v2f* rO = &sdO[ci][2 * ty + 1 + kj][tx];
                v2f e0 = rE[0], o0 = rO[0], e1 = rE[1], o1 = rO[1];
                tap4(e0, w0, aA1); tap4(o0, w0, aB1);
                tap4(o0, w1, aA1); tap4(e1, w1, aB1);
                tap4(e1, w2, aA1); tap4(o1, w2, aB1);
            }
        }
    }
    NC_STORE22(Hh, Ww)
}

// ---------------------------------------------------------------------------
// Fused: 1x1 nconv 4->1 (w7) on packed (478,638) + adaptive pool -> (480,640).
// ---------------------------------------------------------------------------
__global__ __launch_bounds__(256) void finalk(
    const float4* __restrict__ x4, const float4* __restrict__ c4,
    const float* __restrict__ w7, const float* __restrict__ b7,
    float* __restrict__ out)
{
    __shared__ float sw[5];
    if (threadIdx.x < 4) sw[threadIdx.x] = softplusf(w7[threadIdx.x]);
    if (threadIdx.x == 4) sw[4] = b7[0];
    __syncthreads();

    const int HI = 478, WI = 638, HO = 480, WO = 640;
    int total = 8 * HO * WO;
    int i = blockIdx.x * 256 + threadIdx.x;
    if (i >= total) return;
    int ow = i % WO;
    int oh = (i / WO) % HO;
    int b  = i / (WO * HO);
    float w0 = sw[0], w1 = sw[1], w2 = sw[2], w3 = sw[3], bias = sw[4];

    int sh = (oh * HI) / HO, eh = ((oh + 1) * HI + HO - 1) / HO;
    int sw_ = (ow * WI) / WO, ew = ((ow + 1) * WI + WO - 1) / WO;
    float s = 0.f;
    for (int ih = sh; ih < eh; ++ih)
        for (int iw = sw_; iw < ew; ++iw) {
            size_t t = ((size_t)b * HI + ih) * WI + iw;
            float4 cc = c4[t], xx = x4[t];
            float den = w0 * cc.x + w1 * cc.y + w2 * cc.z + w3 * cc.w;
            float nomv = w0 * xx.x * cc.x + w1 * xx.y * cc.y
                       + w2 * xx.z * cc.z + w3 * xx.w * cc.w;
            s += nomv * rcpf(den + EPSN) + bias;
        }
    out[i] = s * rcpf((float)((eh - sh) * (ew - sw_)));
}

// ---------------------------------------------------------------------------
extern "C" void kernel_launch(void* const* d_in, const int* in_sizes, int n_in,
                              void* d_out, int out_size, void* d_ws, size_t ws_size,
                              hipStream_t stream)
{
    const float* S   = (const float*)d_in[1];
    const float* w1  = (const float*)d_in[3];  const float* b1  = (const float*)d_in[4];
    const float* w2  = (const float*)d_in[5];  const float* b2  = (const float*)d_in[6];
    const float* w3  = (const float*)d_in[7];  const float* b3  = (const float*)d_in[8];
    const float* w4  = (const float*)d_in[9];  const float* b4  = (const float*)d_in[10];
    const float* w5  = (const float*)d_in[11]; const float* b5  = (const float*)d_in[12];
    const float* w6  = (const float*)d_in[13]; const float* b6  = (const float*)d_in[14];
    const float* w65 = (const float*)d_in[15]; const float* b65 = (const float*)d_in[16];
    const float* w7  = (const float*)d_in[17]; const float* b7  = (const float*)d_in[18];
    float* out = (float*)d_out;
    float* ws  = (float*)d_ws;

    const size_t FULL = 9830400, HALF = 2457600, QUAR = 614400, EIGH = 153600;
    float4 *A0 = (float4*)ws,              *A1 = (float4*)(ws + FULL),
           *A2 = (float4*)(ws + 2*FULL),   *A3 = (float4*)(ws + 3*FULL);
    float4 *P0 = (float4*)(ws + 4*FULL),            *P1 = (float4*)(ws + 4*FULL + HALF),
           *P2 = (float4*)(ws + 4*FULL + 2*HALF),   *P3 = (float4*)(ws + 4*FULL + 3*HALF);
    float4 *Q0 = (float4*)(ws + 4*FULL + 4*HALF),          *Q1 = (float4*)(ws + 4*FULL + 4*HALF + QUAR),
           *Q2 = (float4*)(ws + 4*FULL + 4*HALF + 2*QUAR), *Q3 = (float4*)(ws + 4*FULL + 4*HALF + 3*QUAR);
    float4 *E0 = (float4*)(ws + 4*FULL + 4*HALF + 4*QUAR),
           *E1 = (float4*)(ws + 4*FULL + 4*HALF + 4*QUAR + EIGH),
           *E2 = (float4*)(ws + 4*FULL + 4*HALF + 4*QUAR + 2*EIGH),
           *E3 = (float4*)(ws + 4*FULL + 4*HALF + 4*QUAR + 3*EIGH);

    dim3 blk(16, 16);
    auto grd16 = [](int Ho, int Wo) { return dim3((Wo + 31) / 32, (Ho + 15) / 16, 8); };
    auto grd32 = [](int Ho, int Wo) { return dim3((Wo + 31) / 32, (Ho + 31) / 32, 8); };

    // encoder, full res
    nconv5_first<<<grd16(480, 640), blk, 0, stream>>>(S, w1, b1, A0, A1, 480, 640);
    nconv5p4<<<grd32(480, 640), blk, 0, stream>>>(A0, A1, w2, b2, A2, A3, 480, 640);
    nconv5p4<<<grd32(480, 640), blk, 0, stream>>>(A2, A3, w3, b3, A0, A1, 480, 640);   // x1,c1
    // 1/2 scale
    pool2k<<<(8 * 240 * 320 + 255) / 256, 256, 0, stream>>>(A0, A1, P0, P1, 480, 640);
    nconv5p4<<<grd32(240, 320), blk, 0, stream>>>(P0, P1, w2, b2, P2, P3, 240, 320);
    nconv5p4<<<grd32(240, 320), blk, 0, stream>>>(P2, P3, w3, b3, P0, P1, 240, 320);   // x2_ds
    // 1/4 scale
    pool2k<<<(8 * 120 * 160 + 255) / 256, 256, 0, stream>>>(P0, P1, Q0, Q1, 240, 320);
    nconv5p4<<<grd32(120, 160), blk, 0, stream>>>(Q0, Q1, w2, b2, Q2, Q3, 120, 160);   // x3_ds
    // 1/8 scale
    pool2k<<<(8 * 60 * 80 + 255) / 256, 256, 0, stream>>>(Q2, Q3, E0, E1, 120, 160);
    nconv5p4<<<grd32(60, 80), blk, 0, stream>>>(E0, E1, w2, b2, E2, E3, 60, 80);       // x4_ds
    // decoder
    nconv3cat<false, 1><<<grd32(120, 160), blk, 0, stream>>>(Q2, Q3, E2, E3, w4, b4, Q0, Q1, 120, 160);
    nconv3cat<false, 1><<<grd32(240, 320), blk, 0, stream>>>(P0, P1, Q0, Q1, w5, b5, P2, P3, 240, 320);
    nconv3cat<true , 0><<<grd32(478, 638), blk, 0, stream>>>(A0, A1, P2, P3, w6, b6, A2, A3, 480, 640);
    nconv3p<<<grd32(478, 638), blk, 0, stream>>>(A2, A3, w65, b65, A0, A1, 478, 638);
    finalk<<<(8 * 480 * 640 + 255) / 256, 256, 0, stream>>>(A0, A1, w7, b7, out);
}

// Round 10
// 369.861 us; speedup vs baseline: 1.1858x; 1.1858x over previous
//
#include <hip/hip_runtime.h>

// NConv depth-completion net, fp32. R10:
// - v_pk_fma_f32 with LEGAL operands: acc packed across out-channel pairs
//   (D01,D23,N01,N23). w01/w23 pairs come straight from the float4 weight
//   read; tap {c,xc} broadcast half via op_sel (R9 failed: scalar src0).
//     den: op_sel:[0,0,0] op_sel_hi:[1,0,1]  (v.lo = c for both halves)
//     nom: op_sel:[0,1,0] op_sel_hi:[1,1,1]  (v.hi = xc for both halves)
// - 2x2 argmax-pool fused into producing conv (template<POOL>): horizontal
//   pair in-thread, vertical via __shfl_down(16) same wave. 3 pool2k
//   dispatches eliminated.
// - Everything else R7-identical (best: 404us).

#define EPSN 1e-20f

typedef float v2f __attribute__((ext_vector_type(2)));

__device__ __forceinline__ float softplusf(float x) {
    return fmaxf(x, 0.f) + log1pf(expf(-fabsf(x)));
}
__device__ __forceinline__ float rcpf(float x) { return __builtin_amdgcn_rcpf(x); }

// Sum s_w4[0..n) across wave 0; lane 0 writes *dst. Needs __syncthreads after.
__device__ __forceinline__ void wsum4(const float4* s_w4, int n, int tid, float4* dst)
{
    if (tid < 64) {
        float4 a = make_float4(0.f, 0.f, 0.f, 0.f);
        for (int i = tid; i < n; i += 64) {
            float4 w = s_w4[i];
            a.x += w.x; a.y += w.y; a.z += w.z; a.w += w.w;
        }
        #pragma unroll
        for (int off = 32; off; off >>= 1) {
            a.x += __shfl_xor(a.x, off);
            a.y += __shfl_xor(a.y, off);
            a.z += __shfl_xor(a.z, off);
            a.w += __shfl_xor(a.w, off);
        }
        if (tid == 0) *dst = a;
    }
}

// acc layout: a[0]={den0,den1} a[1]={den2,den3} a[2]={nom0,nom1} a[3]={nom2,nom3}
// v = {c, xc}; w01 = {w_c0,w_c1}; w23 = {w_c2,w_c3}. 4 pk_fma per tap.
__device__ __forceinline__ void tap4(v2f v, v2f w01, v2f w23, v2f* a)
{
    asm("v_pk_fma_f32 %0, %1, %2, %0 op_sel:[0,0,0] op_sel_hi:[1,0,1]"
        : "+v"(a[0]) : "v"(w01), "v"(v));
    asm("v_pk_fma_f32 %0, %1, %2, %0 op_sel:[0,0,0] op_sel_hi:[1,0,1]"
        : "+v"(a[1]) : "v"(w23), "v"(v));
    asm("v_pk_fma_f32 %0, %1, %2, %0 op_sel:[0,1,0] op_sel_hi:[1,1,1]"
        : "+v"(a[2]) : "v"(w01), "v"(v));
    asm("v_pk_fma_f32 %0, %1, %2, %0 op_sel:[0,1,0] op_sel_hi:[1,1,1]"
        : "+v"(a[3]) : "v"(w23), "v"(v));
}
#define TAP2(W01, W23, VA, VB)  tap4((VA),(W01),(W23),aA); tap4((VB),(W01),(W23),aB);

// Build output (x,c) float4s from an acc set.
#define NC_EPI(A, XO, CO)                                            \
    XO.x = A[2].x*rcpf(A[0].x+EPSN)+bias.x; CO.x = A[0].x*rs0;       \
    XO.y = A[2].y*rcpf(A[0].y+EPSN)+bias.y; CO.y = A[0].y*rs1;       \
    XO.z = A[3].x*rcpf(A[1].x+EPSN)+bias.z; CO.z = A[1].x*rs2;       \
    XO.w = A[3].y*rcpf(A[1].y+EPSN)+bias.w; CO.w = A[1].y*rs3;

#define NC_STORE_PACKED(HOUT, WOUT)                                         \
    {                                                                       \
        const int oh = oh0 + ty, ow = ow0 + 2 * tx;                         \
        if (oh < (HOUT) && ow < (WOUT)) {                                   \
            float4 bias = s_bias, ssum = s_sum;                             \
            float rs0=rcpf(ssum.x), rs1=rcpf(ssum.y),                       \
                  rs2=rcpf(ssum.z), rs3=rcpf(ssum.w);                       \
            size_t t = ((size_t)b * (HOUT) + oh) * (WOUT) + ow;             \
            float4 xo, co;                                                  \
            NC_EPI(aA, xo, co)                                              \
            xout4[t] = xo; cout4[t] = co;                                   \
            if (ow + 1 < (WOUT)) {                                          \
                NC_EPI(aB, xo, co)                                          \
                xout4[t+1] = xo; cout4[t+1] = co;                           \
            }                                                               \
        }                                                                   \
    }

// ---------------------------------------------------------------------------
// First 5x5 nconv: planar S in (c0 = S>0.01 on the fly), packed out. 32x16.
// ---------------------------------------------------------------------------
__global__ __launch_bounds__(256) void nconv5_first(
    const float* __restrict__ S,
    const float* __restrict__ wraw, const float* __restrict__ braw,
    float4* __restrict__ xout4, float4* __restrict__ cout4,
    int Hh, int Ww)
{
    __shared__ v2f sdE[20][19], sdO[20][19];
    __shared__ float4 s_w4[25];
    __shared__ float4 s_sum, s_bias;
    const int b = blockIdx.z;
    const int oh0 = blockIdx.y * 16, ow0 = blockIdx.x * 32;
    const int tx = threadIdx.x, ty = threadIdx.y, tid = ty * 16 + tx;

    if (tid < 25) {
        float4 w;
        w.x = softplusf(wraw[tid]);      w.y = softplusf(wraw[25 + tid]);
        w.z = softplusf(wraw[50 + tid]); w.w = softplusf(wraw[75 + tid]);
        s_w4[tid] = w;
    }
    if (tid == 0) s_bias = make_float4(braw[0], braw[1], braw[2], braw[3]);
    __syncthreads();

    for (int i = tid; i < 20 * 18; i += 256) {
        int ly = i / 18, j = i - ly * 18;
        int ih = oh0 - 2 + ly, iw = ow0 - 2 + 2 * j;   // iw even
        float s0 = 0.f, s1 = 0.f;
        if ((unsigned)ih < (unsigned)Hh && iw >= 0 && iw < Ww - 1) {
            float2 t = *(const float2*)&S[((size_t)b * Hh + ih) * Ww + iw];
            s0 = t.x; s1 = t.y;
        }
        float c0 = (s0 > 0.01f) ? 1.f : 0.f;
        float c1 = (s1 > 0.01f) ? 1.f : 0.f;
        sdE[ly][j] = (v2f){c0, s0 * c0};
        sdO[ly][j] = (v2f){c1, s1 * c1};
    }
    wsum4(s_w4, 25, tid, &s_sum);
    __syncthreads();

    v2f aA[4] = {}, aB[4] = {};
    #pragma unroll
    for (int kj = 0; kj < 5; ++kj) {
        const v2f* rE = &sdE[ty + kj][tx];
        const v2f* rO = &sdO[ty + kj][tx];
        v2f e0 = rE[0], o0 = rO[0], e1 = rE[1], o1 = rO[1], e2 = rE[2], o2 = rO[2];
        const v2f* wr = (const v2f*)&s_w4[kj * 5];
        TAP2(wr[0], wr[1], e0, o0)
        TAP2(wr[2], wr[3], o0, e1)
        TAP2(wr[4], wr[5], e1, o1)
        TAP2(wr[6], wr[7], o1, e2)
        TAP2(wr[8], wr[9], e2, o2)
    }
    NC_STORE_PACKED(Hh, Ww)
}

// ---------------------------------------------------------------------------
// 5x5 nconv, CI=4, packed in/out. 32x16 tile, 2 px/thread, parity LDS.
// POOL: additionally emit 2x2 argmax-of-c pooled (x, c/4) at half res.
// ---------------------------------------------------------------------------
template<bool POOL>
__global__ __launch_bounds__(256) void nconv5p4(
    const float4* __restrict__ xin4, const float4* __restrict__ cin4,
    const float* __restrict__ wraw, const float* __restrict__ braw,
    float4* __restrict__ xout4, float4* __restrict__ cout4,
    float4* __restrict__ xo_p, float4* __restrict__ co_p,
    int Hh, int Ww)
{
    __shared__ v2f sdE[4][20][19], sdO[4][20][19];
    __shared__ float4 s_w4[100];
    __shared__ float4 s_sum, s_bias;
    const int b = blockIdx.z;
    const int oh0 = blockIdx.y * 16, ow0 = blockIdx.x * 32;
    const int tx = threadIdx.x, ty = threadIdx.y, tid = ty * 16 + tx;

    if (tid < 100) {
        float4 w;
        w.x = softplusf(wraw[tid]);       w.y = softplusf(wraw[100 + tid]);
        w.z = softplusf(wraw[200 + tid]); w.w = softplusf(wraw[300 + tid]);
        s_w4[tid] = w;
    }
    if (tid == 0) s_bias = make_float4(braw[0], braw[1], braw[2], braw[3]);
    __syncthreads();

    const float4 z = make_float4(0.f, 0.f, 0.f, 0.f);
    for (int i = tid; i < 20 * 18; i += 256) {
        int ly = i / 18, j = i - ly * 18;
        int ih = oh0 - 2 + ly, iw = ow0 - 2 + 2 * j;
        float4 cA = z, xA = z, cB = z, xB = z;
        if ((unsigned)ih < (unsigned)Hh) {
            size_t rb = ((size_t)b * Hh + ih) * Ww;
            if ((unsigned)iw < (unsigned)Ww)       { cA = cin4[rb + iw];     xA = xin4[rb + iw]; }
            if ((unsigned)(iw + 1) < (unsigned)Ww) { cB = cin4[rb + iw + 1]; xB = xin4[rb + iw + 1]; }
        }
        sdE[0][ly][j] = (v2f){cA.x, xA.x * cA.x};
        sdE[1][ly][j] = (v2f){cA.y, xA.y * cA.y};
        sdE[2][ly][j] = (v2f){cA.z, xA.z * cA.z};
        sdE[3][ly][j] = (v2f){cA.w, xA.w * cA.w};
        sdO[0][ly][j] = (v2f){cB.x, xB.x * cB.x};
        sdO[1][ly][j] = (v2f){cB.y, xB.y * cB.y};
        sdO[2][ly][j] = (v2f){cB.z, xB.z * cB.z};
        sdO[3][ly][j] = (v2f){cB.w, xB.w * cB.w};
    }
    wsum4(s_w4, 100, tid, &s_sum);
    __syncthreads();

    v2f aA[4] = {}, aB[4] = {};
    #pragma unroll 1
    for (int ci = 0; ci < 4; ++ci) {
        #pragma unroll
        for (int kj = 0; kj < 5; ++kj) {
            const v2f* rE = &sdE[ci][ty + kj][tx];
            const v2f* rO = &sdO[ci][ty + kj][tx];
            v2f e0 = rE[0], o0 = rO[0], e1 = rE[1], o1 = rO[1], e2 = rE[2], o2 = rO[2];
            const v2f* wr = (const v2f*)&s_w4[ci * 25 + kj * 5];
            TAP2(wr[0], wr[1], e0, o0)
            TAP2(wr[2], wr[3], o0, e1)
            TAP2(wr[4], wr[5], e1, o1)
            TAP2(wr[6], wr[7], o1, e2)
            TAP2(wr[8], wr[9], e2, o2)
        }
    }

    const int oh = oh0 + ty, ow = ow0 + 2 * tx;
    float4 bias = s_bias, ssum = s_sum;
    float rs0 = rcpf(ssum.x), rs1 = rcpf(ssum.y),
          rs2 = rcpf(ssum.z), rs3 = rcpf(ssum.w);
    float4 xoA, coA, xoB, coB;
    NC_EPI(aA, xoA, coA)
    NC_EPI(aB, xoB, coB)
    const bool rowok = oh < Hh, colA = ow < Ww, colB = ow + 1 < Ww;
    if (rowok && colA) {
        size_t t = ((size_t)b * Hh + oh) * Ww + ow;
        xout4[t] = xoA; cout4[t] = coA;
        if (colB) { xout4[t + 1] = xoB; cout4[t + 1] = coB; }
    }
    if (POOL) {
        // local best of horizontal pair (order: col0 then col1, strict >)
        float4 cb = coA, xb = xoA;
        if (coB.x > cb.x) { cb.x = coB.x; xb.x = xoB.x; }
        if (coB.y > cb.y) { cb.y = coB.y; xb.y = xoB.y; }
        if (coB.z > cb.z) { cb.z = coB.z; xb.z = xoB.z; }
        if (coB.w > cb.w) { cb.w = coB.w; xb.w = xoB.w; }
        // vertical partner: lane + 16 (row oh+1), same wave
        float4 cb2, xb2;
        cb2.x = __shfl_down(cb.x, 16); xb2.x = __shfl_down(xb.x, 16);
        cb2.y = __shfl_down(cb.y, 16); xb2.y = __shfl_down(xb.y, 16);
        cb2.z = __shfl_down(cb.z, 16); xb2.z = __shfl_down(xb.z, 16);
        cb2.w = __shfl_down(cb.w, 16); xb2.w = __shfl_down(xb.w, 16);
        if (!(ty & 1) && rowok && colA) {
            if (cb2.x > cb.x) { cb.x = cb2.x; xb.x = xb2.x; }
            if (cb2.y > cb.y) { cb.y = cb2.y; xb.y = xb2.y; }
            if (cb2.z > cb.z) { cb.z = cb2.z; xb.z = xb2.z; }
            if (cb2.w > cb.w) { cb.w = cb2.w; xb.w = xb2.w; }
            cb.x *= 0.25f; cb.y *= 0.25f; cb.z *= 0.25f; cb.w *= 0.25f;
            size_t tp = ((size_t)b * (Hh >> 1) + (oh >> 1)) * (Ww >> 1) + (ow >> 1);
            xo_p[tp] = xb; co_p[tp] = cb;
        }
    }
}

// ---------------------------------------------------------------------------
// 3x3 nconv over concat{direct 4ch (Hin,Win), nearest-2x-up 4ch (Hin/2,Win/2)}.
// Up staged at native half-res. 32x16 tile, 2 px/thread, parity LDS (direct).
// UP_FIRST: up occupies weight channels 0-3 (w6) else 4-7 (w4,w5).
// ---------------------------------------------------------------------------
template<bool UP_FIRST, int PAD>
__global__ __launch_bounds__(256) void nconv3cat(
    const float4* __restrict__ xd4, const float4* __restrict__ cd4,
    const float4* __restrict__ xu4, const float4* __restrict__ cu4,
    const float* __restrict__ wraw, const float* __restrict__ braw,
    float4* __restrict__ xout4, float4* __restrict__ cout4,
    int Hin, int Win)
{
    __shared__ v2f sdE[4][18][18], sdO[4][18][18];   // direct, parity cols
    __shared__ v2f sup[4][10][19];                   // up, native half-res
    __shared__ float4 s_w4[72];
    __shared__ float4 s_sum, s_bias;

    const int Hout = Hin - 2 + 2 * PAD, Wout = Win - 2 + 2 * PAD;
    const int Hu = Hin / 2, Wu = Win / 2;
    const int b = blockIdx.z;
    const int oh0 = blockIdx.y * 16, ow0 = blockIdx.x * 32;
    const int tx = threadIdx.x, ty = threadIdx.y, tid = ty * 16 + tx;

    if (tid < 72) {
        float4 w;
        w.x = softplusf(wraw[tid]);       w.y = softplusf(wraw[72 + tid]);
        w.z = softplusf(wraw[144 + tid]); w.w = softplusf(wraw[216 + tid]);
        s_w4[tid] = w;
    }
    if (tid == 0) s_bias = make_float4(braw[0], braw[1], braw[2], braw[3]);
    __syncthreads();

    const float4 z = make_float4(0.f, 0.f, 0.f, 0.f);
    for (int i = tid; i < 18 * 17; i += 256) {          // direct: 18 rows x 17 pairs
        int ly = i / 17, j = i - ly * 17;
        int ih = oh0 - PAD + ly, iw = ow0 - PAD + 2 * j;
        float4 cA = z, xA = z, cB = z, xB = z;
        if ((unsigned)ih < (unsigned)Hin) {
            size_t rb = ((size_t)b * Hin + ih) * Win;
            if ((unsigned)iw < (unsigned)Win)       { cA = cd4[rb + iw];     xA = xd4[rb + iw]; }
            if ((unsigned)(iw + 1) < (unsigned)Win) { cB = cd4[rb + iw + 1]; xB = xd4[rb + iw + 1]; }
        }
        sdE[0][ly][j] = (v2f){cA.x, xA.x * cA.x};
        sdE[1][ly][j] = (v2f){cA.y, xA.y * cA.y};
        sdE[2][ly][j] = (v2f){cA.z, xA.z * cA.z};
        sdE[3][ly][j] = (v2f){cA.w, xA.w * cA.w};
        sdO[0][ly][j] = (v2f){cB.x, xB.x * cB.x};
        sdO[1][ly][j] = (v2f){cB.y, xB.y * cB.y};
        sdO[2][ly][j] = (v2f){cB.z, xB.z * cB.z};
        sdO[3][ly][j] = (v2f){cB.w, xB.w * cB.w};
    }
    const int ru0 = (oh0 - PAD) >> 1, cu0 = (ow0 - PAD) >> 1;
    for (int i = tid; i < 10 * 18; i += 256) {          // up: 10 rows x 18 cols
        int r = i / 18, k = i - r * 18;
        int ur = ru0 + r, uc = cu0 + k;
        float4 cU = z, xU = z;
        if ((unsigned)ur < (unsigned)Hu && (unsigned)uc < (unsigned)Wu) {
            size_t t = ((size_t)b * Hu + ur) * Wu + uc;
            cU = cu4[t]; xU = xu4[t];
        }
        sup[0][r][k] = (v2f){cU.x, xU.x * cU.x};
        sup[1][r][k] = (v2f){cU.y, xU.y * cU.y};
        sup[2][r][k] = (v2f){cU.z, xU.z * cU.z};
        sup[3][r][k] = (v2f){cU.w, xU.w * cU.w};
    }
    wsum4(s_w4, 72, tid, &s_sum);
    __syncthreads();

    v2f aA[4] = {}, aB[4] = {};
    #pragma unroll 1
    for (int ci = 0; ci < 4; ++ci) {
        const int chD = UP_FIRST ? ci + 4 : ci;
        const int chU = UP_FIRST ? ci : ci + 4;
        #pragma unroll
        for (int kj = 0; kj < 3; ++kj) {
            const v2f* rE = &sdE[ci][ty + kj][tx];
            const v2f* rO = &sdO[ci][ty + kj][tx];
            v2f e0 = rE[0], o0 = rO[0], e1 = rE[1], o1 = rO[1];
            const v2f* wr = (const v2f*)&s_w4[chD * 9 + kj * 3];
            TAP2(wr[0], wr[1], e0, o0)
            TAP2(wr[2], wr[3], o0, e1)
            TAP2(wr[4], wr[5], e1, o1)
        }
        #pragma unroll
        for (int kj = 0; kj < 3; ++kj) {
            int lyu = (ty + kj + PAD) >> 1;
            const v2f* ru = &sup[ci][lyu][tx];
            v2f u0 = ru[0], u1 = ru[1];
            v2f q0, q1, q2, q3;
            if (PAD == 1) {
                v2f u2 = ru[2];
                q0 = u0; q1 = u1; q2 = u1; q3 = u2;   // idx = (m+1)>>1
            } else {
                q0 = u0; q1 = u0; q2 = u1; q3 = u1;   // idx = m>>1
            }
            const v2f* wr = (const v2f*)&s_w4[chU * 9 + kj * 3];
            TAP2(wr[0], wr[1], q0, q1)
            TAP2(wr[2], wr[3], q1, q2)
            TAP2(wr[4], wr[5], q2, q3)
        }
    }
    NC_STORE_PACKED(Hout, Wout)
}

// ---------------------------------------------------------------------------
// 3x3 nconv, 4->4, pad=1 (w65), packed. 32x16 tile, 2 px/thread, parity LDS.
// ---------------------------------------------------------------------------
__global__ __launch_bounds__(256) void nconv3p(
    const float4* __restrict__ xin4, const float4* __restrict__ cin4,
    const float* __restrict__ wraw, const float* __restrict__ braw,
    float4* __restrict__ xout4, float4* __restrict__ cout4,
    int Hh, int Ww)
{
    __shared__ v2f sdE[4][18][18], sdO[4][18][18];
    __shared__ float4 s_w4[36];
    __shared__ float4 s_sum, s_bias;
    const int b = blockIdx.z;
    const int oh0 = blockIdx.y * 16, ow0 = blockIdx.x * 32;
    const int tx = threadIdx.x, ty = threadIdx.y, tid = ty * 16 + tx;

    if (tid < 36) {
        float4 w;
        w.x = softplusf(wraw[tid]);      w.y = softplusf(wraw[36 + tid]);
        w.z = softplusf(wraw[72 + tid]); w.w = softplusf(wraw[108 + tid]);
        s_w4[tid] = w;
    }
    if (tid == 0) s_bias = make_float4(braw[0], braw[1], braw[2], braw[3]);
    __syncthreads();

    const float4 z = make_float4(0.f, 0.f, 0.f, 0.f);
    for (int i = tid; i < 18 * 17; i += 256) {
        int ly = i / 17, j = i - ly * 17;
        int ih = oh0 - 1 + ly, iw = ow0 - 1 + 2 * j;
        float4 cA = z, xA = z, cB = z, xB = z;
        if ((unsigned)ih < (unsigned)Hh) {
            size_t rb = ((size_t)b * Hh + ih) * Ww;
            if ((unsigned)iw < (unsigned)Ww)       { cA = cin4[rb + iw];     xA = xin4[rb + iw]; }
            if ((unsigned)(iw + 1) < (unsigned)Ww) { cB = cin4[rb + iw + 1]; xB = xin4[rb + iw + 1]; }
        }
        sdE[0][ly][j] = (v2f){cA.x, xA.x * cA.x};
        sdE[1][ly][j] = (v2f){cA.y, xA.y * cA.y};
        sdE[2][ly][j] = (v2f){cA.z, xA.z * cA.z};
        sdE[3][ly][j] = (v2f){cA.w, xA.w * cA.w};
        sdO[0][ly][j] = (v2f){cB.x, xB.x * cB.x};
        sdO[1][ly][j] = (v2f){cB.y, xB.y * cB.y};
        sdO[2][ly][j] = (v2f){cB.z, xB.z * cB.z};
        sdO[3][ly][j] = (v2f){cB.w, xB.w * cB.w};
    }
    wsum4(s_w4, 36, tid, &s_sum);
    __syncthreads();

    v2f aA[4] = {}, aB[4] = {};
    #pragma unroll 1
    for (int ci = 0; ci < 4; ++ci) {
        #pragma unroll
        for (int kj = 0; kj < 3; ++kj) {
            const v2f* rE = &sdE[ci][ty + kj][tx];
            const v2f* rO = &sdO[ci][ty + kj][tx];
            v2f e0 = rE[0], o0 = rO[0], e1 = rE[1], o1 = rO[1];
            const v2f* wr = (const v2f*)&s_w4[ci * 9 + kj * 3];
            TAP2(wr[0], wr[1], e0, o0)
            TAP2(wr[2], wr[3], o0, e1)
            TAP2(wr[4], wr[5], e1, o1)
        }
    }
    NC_STORE_PACKED(Hh, Ww)
}

// ---------------------------------------------------------------------------
// Fused: 1x1 nconv 4->1 (w7) on packed (478,638) + adaptive pool -> (480,640).
// ---------------------------------------------------------------------------
__global__ __launch_bounds__(256) void finalk(
    const float4* __restrict__ x4, const float4* __restrict__ c4,
    const float* __restrict__ w7, const float* __restrict__ b7,
    float* __restrict__ out)
{
    __shared__ float sw[5];
    if (threadIdx.x < 4) sw[threadIdx.x] = softplusf(w7[threadIdx.x]);
    if (threadIdx.x == 4) sw[4] = b7[0];
    __syncthreads();

    const int HI = 478, WI = 638, HO = 480, WO = 640;
    int total = 8 * HO * WO;
    int i = blockIdx.x * 256 + threadIdx.x;
    if (i >= total) return;
    int ow = i % WO;
    int oh = (i / WO) % HO;
    int b  = i / (WO * HO);
    float w0 = sw[0], w1 = sw[1], w2 = sw[2], w3 = sw[3], bias = sw[4];

    int sh = (oh * HI) / HO, eh = ((oh + 1) * HI + HO - 1) / HO;
    int sw_ = (ow * WI) / WO, ew = ((ow + 1) * WI + WO - 1) / WO;
    float s = 0.f;
    for (int ih = sh; ih < eh; ++ih)
        for (int iw = sw_; iw < ew; ++iw) {
            size_t t = ((size_t)b * HI + ih) * WI + iw;
            float4 cc = c4[t], xx = x4[t];
            float den = w0 * cc.x + w1 * cc.y + w2 * cc.z + w3 * cc.w;
            float nomv = w0 * xx.x * cc.x + w1 * xx.y * cc.y
                       + w2 * xx.z * cc.z + w3 * xx.w * cc.w;
            s += nomv * rcpf(den + EPSN) + bias;
        }
    out[i] = s * rcpf((float)((eh - sh) * (ew - sw_)));
}

// ---------------------------------------------------------------------------
extern "C" void kernel_launch(void* const* d_in, const int* in_sizes, int n_in,
                              void* d_out, int out_size, void* d_ws, size_t ws_size,
                              hipStream_t stream)
{
    const float* S   = (const float*)d_in[1];
    const float* w1  = (const float*)d_in[3];  const float* b1  = (const float*)d_in[4];
    const float* w2  = (const float*)d_in[5];  const float* b2  = (const float*)d_in[6];
    const float* w3  = (const float*)d_in[7];  const float* b3  = (const float*)d_in[8];
    const float* w4  = (const float*)d_in[9];  const float* b4  = (const float*)d_in[10];
    const float* w5  = (const float*)d_in[11]; const float* b5  = (const float*)d_in[12];
    const float* w6  = (const float*)d_in[13]; const float* b6  = (const float*)d_in[14];
    const float* w65 = (const float*)d_in[15]; const float* b65 = (const float*)d_in[16];
    const float* w7  = (const float*)d_in[17]; const float* b7  = (const float*)d_in[18];
    float* out = (float*)d_out;
    float* ws  = (float*)d_ws;

    const size_t FULL = 9830400, HALF = 2457600, QUAR = 614400, EIGH = 153600;
    float4 *A0 = (float4*)ws,              *A1 = (float4*)(ws + FULL),
           *A2 = (float4*)(ws + 2*FULL),   *A3 = (float4*)(ws + 3*FULL);
    float4 *P0 = (float4*)(ws + 4*FULL),            *P1 = (float4*)(ws + 4*FULL + HALF),
           *P2 = (float4*)(ws + 4*FULL + 2*HALF),   *P3 = (float4*)(ws + 4*FULL + 3*HALF);
    float4 *Q0 = (float4*)(ws + 4*FULL + 4*HALF),          *Q1 = (float4*)(ws + 4*FULL + 4*HALF + QUAR),
           *Q2 = (float4*)(ws + 4*FULL + 4*HALF + 2*QUAR), *Q3 = (float4*)(ws + 4*FULL + 4*HALF + 3*QUAR);
    float4 *E0 = (float4*)(ws + 4*FULL + 4*HALF + 4*QUAR),
           *E1 = (float4*)(ws + 4*FULL + 4*HALF + 4*QUAR + EIGH),
           *E2 = (float4*)(ws + 4*FULL + 4*HALF + 4*QUAR + 2*EIGH),
           *E3 = (float4*)(ws + 4*FULL + 4*HALF + 4*QUAR + 3*EIGH);

    dim3 blk(16, 16);
    auto grd = [](int Ho, int Wo) { return dim3((Wo + 31) / 32, (Ho + 15) / 16, 8); };

    // encoder, full res
    nconv5_first<<<grd(480, 640), blk, 0, stream>>>(S, w1, b1, A0, A1, 480, 640);
    nconv5p4<false><<<grd(480, 640), blk, 0, stream>>>(A0, A1, w2, b2, A2, A3, nullptr, nullptr, 480, 640);
    nconv5p4<true ><<<grd(480, 640), blk, 0, stream>>>(A2, A3, w3, b3, A0, A1, P0, P1, 480, 640);  // x1,c1 + pooled
    // 1/2 scale
    nconv5p4<false><<<grd(240, 320), blk, 0, stream>>>(P0, P1, w2, b2, P2, P3, nullptr, nullptr, 240, 320);
    nconv5p4<true ><<<grd(240, 320), blk, 0, stream>>>(P2, P3, w3, b3, P0, P1, Q0, Q1, 240, 320);  // x2_ds + pooled
    // 1/4 scale
    nconv5p4<true ><<<grd(120, 160), blk, 0, stream>>>(Q0, Q1, w2, b2, Q2, Q3, E0, E1, 120, 160);  // x3_ds + pooled
    // 1/8 scale
    nconv5p4<false><<<grd(60, 80), blk, 0, stream>>>(E0, E1, w2, b2, E2, E3, nullptr, nullptr, 60, 80);  // x4_ds
    // decoder
    nconv3cat<false, 1><<<grd(120, 160), blk, 0, stream>>>(Q2, Q3, E2, E3, w4, b4, Q0, Q1, 120, 160);
    nconv3cat<false, 1><<<grd(240, 320), blk, 0, stream>>>(P0, P1, Q0, Q1, w5, b5, P2, P3, 240, 320);
    nconv3cat<true , 0><<<grd(478, 638), blk, 0, stream>>>(A0, A1, P2, P3, w6, b6, A2, A3, 480, 640);
    nconv3p<<<grd(478, 638), blk, 0, stream>>>(A2, A3, w65, b65, A0, A1, 478, 638);
    finalk<<<(8 * 480 * 640 + 255) / 256, 256, 0, stream>>>(A0, A1, w7, b7, out);
}

// Round 11
// 354.703 us; speedup vs baseline: 1.2365x; 1.0427x over previous
//
#include <hip/hip_runtime.h>

// NConv depth-completion net, fp32. R11 = R10 + w7(1x1 nconv) fused into
// nconv3p epilogue: writes one scalar plane (9.7MB) instead of x+c float4
// planes (78MB); finalk's 78MB re-read replaced by a tiny adaptive-pool
// kernel. R10 lesson kept: pk_fma saves issue slots not ALU cycles; conv
// structure (32x16 tile, parity LDS, unroll 1, no minwaves) frozen.

#define EPSN 1e-20f

typedef float v2f __attribute__((ext_vector_type(2)));

__device__ __forceinline__ float softplusf(float x) {
    return fmaxf(x, 0.f) + log1pf(expf(-fabsf(x)));
}
__device__ __forceinline__ float rcpf(float x) { return __builtin_amdgcn_rcpf(x); }

// Sum s_w4[0..n) across wave 0; lane 0 writes *dst. Needs __syncthreads after.
__device__ __forceinline__ void wsum4(const float4* s_w4, int n, int tid, float4* dst)
{
    if (tid < 64) {
        float4 a = make_float4(0.f, 0.f, 0.f, 0.f);
        for (int i = tid; i < n; i += 64) {
            float4 w = s_w4[i];
            a.x += w.x; a.y += w.y; a.z += w.z; a.w += w.w;
        }
        #pragma unroll
        for (int off = 32; off; off >>= 1) {
            a.x += __shfl_xor(a.x, off);
            a.y += __shfl_xor(a.y, off);
            a.z += __shfl_xor(a.z, off);
            a.w += __shfl_xor(a.w, off);
        }
        if (tid == 0) *dst = a;
    }
}

// acc layout: a[0]={den0,den1} a[1]={den2,den3} a[2]={nom0,nom1} a[3]={nom2,nom3}
__device__ __forceinline__ void tap4(v2f v, v2f w01, v2f w23, v2f* a)
{
    asm("v_pk_fma_f32 %0, %1, %2, %0 op_sel:[0,0,0] op_sel_hi:[1,0,1]"
        : "+v"(a[0]) : "v"(w01), "v"(v));
    asm("v_pk_fma_f32 %0, %1, %2, %0 op_sel:[0,0,0] op_sel_hi:[1,0,1]"
        : "+v"(a[1]) : "v"(w23), "v"(v));
    asm("v_pk_fma_f32 %0, %1, %2, %0 op_sel:[0,1,0] op_sel_hi:[1,1,1]"
        : "+v"(a[2]) : "v"(w01), "v"(v));
    asm("v_pk_fma_f32 %0, %1, %2, %0 op_sel:[0,1,0] op_sel_hi:[1,1,1]"
        : "+v"(a[3]) : "v"(w23), "v"(v));
}
#define TAP2(W01, W23, VA, VB)  tap4((VA),(W01),(W23),aA); tap4((VB),(W01),(W23),aB);

// Build output (x,c) float4s from an acc set.
#define NC_EPI(A, XO, CO)                                            \
    XO.x = A[2].x*rcpf(A[0].x+EPSN)+bias.x; CO.x = A[0].x*rs0;       \
    XO.y = A[2].y*rcpf(A[0].y+EPSN)+bias.y; CO.y = A[0].y*rs1;       \
    XO.z = A[3].x*rcpf(A[1].x+EPSN)+bias.z; CO.z = A[1].x*rs2;       \
    XO.w = A[3].y*rcpf(A[1].y+EPSN)+bias.w; CO.w = A[1].y*rs3;

#define NC_STORE_PACKED(HOUT, WOUT)                                         \
    {                                                                       \
        const int oh = oh0 + ty, ow = ow0 + 2 * tx;                         \
        if (oh < (HOUT) && ow < (WOUT)) {                                   \
            float4 bias = s_bias, ssum = s_sum;                             \
            float rs0=rcpf(ssum.x), rs1=rcpf(ssum.y),                       \
                  rs2=rcpf(ssum.z), rs3=rcpf(ssum.w);                       \
            size_t t = ((size_t)b * (HOUT) + oh) * (WOUT) + ow;             \
            float4 xo, co;                                                  \
            NC_EPI(aA, xo, co)                                              \
            xout4[t] = xo; cout4[t] = co;                                   \
            if (ow + 1 < (WOUT)) {                                          \
                NC_EPI(aB, xo, co)                                          \
                xout4[t+1] = xo; cout4[t+1] = co;                           \
            }                                                               \
        }                                                                   \
    }

// ---------------------------------------------------------------------------
// First 5x5 nconv: planar S in (c0 = S>0.01 on the fly), packed out. 32x16.
// ---------------------------------------------------------------------------
__global__ __launch_bounds__(256) void nconv5_first(
    const float* __restrict__ S,
    const float* __restrict__ wraw, const float* __restrict__ braw,
    float4* __restrict__ xout4, float4* __restrict__ cout4,
    int Hh, int Ww)
{
    __shared__ v2f sdE[20][19], sdO[20][19];
    __shared__ float4 s_w4[25];
    __shared__ float4 s_sum, s_bias;
    const int b = blockIdx.z;
    const int oh0 = blockIdx.y * 16, ow0 = blockIdx.x * 32;
    const int tx = threadIdx.x, ty = threadIdx.y, tid = ty * 16 + tx;

    if (tid < 25) {
        float4 w;
        w.x = softplusf(wraw[tid]);      w.y = softplusf(wraw[25 + tid]);
        w.z = softplusf(wraw[50 + tid]); w.w = softplusf(wraw[75 + tid]);
        s_w4[tid] = w;
    }
    if (tid == 0) s_bias = make_float4(braw[0], braw[1], braw[2], braw[3]);
    __syncthreads();

    for (int i = tid; i < 20 * 18; i += 256) {
        int ly = i / 18, j = i - ly * 18;
        int ih = oh0 - 2 + ly, iw = ow0 - 2 + 2 * j;   // iw even
        float s0 = 0.f, s1 = 0.f;
        if ((unsigned)ih < (unsigned)Hh && iw >= 0 && iw < Ww - 1) {
            float2 t = *(const float2*)&S[((size_t)b * Hh + ih) * Ww + iw];
            s0 = t.x; s1 = t.y;
        }
        float c0 = (s0 > 0.01f) ? 1.f : 0.f;
        float c1 = (s1 > 0.01f) ? 1.f : 0.f;
        sdE[ly][j] = (v2f){c0, s0 * c0};
        sdO[ly][j] = (v2f){c1, s1 * c1};
    }
    wsum4(s_w4, 25, tid, &s_sum);
    __syncthreads();

    v2f aA[4] = {}, aB[4] = {};
    #pragma unroll
    for (int kj = 0; kj < 5; ++kj) {
        const v2f* rE = &sdE[ty + kj][tx];
        const v2f* rO = &sdO[ty + kj][tx];
        v2f e0 = rE[0], o0 = rO[0], e1 = rE[1], o1 = rO[1], e2 = rE[2], o2 = rO[2];
        const v2f* wr = (const v2f*)&s_w4[kj * 5];
        TAP2(wr[0], wr[1], e0, o0)
        TAP2(wr[2], wr[3], o0, e1)
        TAP2(wr[4], wr[5], e1, o1)
        TAP2(wr[6], wr[7], o1, e2)
        TAP2(wr[8], wr[9], e2, o2)
    }
    NC_STORE_PACKED(Hh, Ww)
}

// ---------------------------------------------------------------------------
// 5x5 nconv, CI=4, packed in/out. 32x16 tile, 2 px/thread, parity LDS.
// POOL: additionally emit 2x2 argmax-of-c pooled (x, c/4) at half res.
// ---------------------------------------------------------------------------
template<bool POOL>
__global__ __launch_bounds__(256) void nconv5p4(
    const float4* __restrict__ xin4, const float4* __restrict__ cin4,
    const float* __restrict__ wraw, const float* __restrict__ braw,
    float4* __restrict__ xout4, float4* __restrict__ cout4,
    float4* __restrict__ xo_p, float4* __restrict__ co_p,
    int Hh, int Ww)
{
    __shared__ v2f sdE[4][20][19], sdO[4][20][19];
    __shared__ float4 s_w4[100];
    __shared__ float4 s_sum, s_bias;
    const int b = blockIdx.z;
    const int oh0 = blockIdx.y * 16, ow0 = blockIdx.x * 32;
    const int tx = threadIdx.x, ty = threadIdx.y, tid = ty * 16 + tx;

    if (tid < 100) {
        float4 w;
        w.x = softplusf(wraw[tid]);       w.y = softplusf(wraw[100 + tid]);
        w.z = softplusf(wraw[200 + tid]); w.w = softplusf(wraw[300 + tid]);
        s_w4[tid] = w;
    }
    if (tid == 0) s_bias = make_float4(braw[0], braw[1], braw[2], braw[3]);
    __syncthreads();

    const float4 z = make_float4(0.f, 0.f, 0.f, 0.f);
    for (int i = tid; i < 20 * 18; i += 256) {
        int ly = i / 18, j = i - ly * 18;
        int ih = oh0 - 2 + ly, iw = ow0 - 2 + 2 * j;
        float4 cA = z, xA = z, cB = z, xB = z;
        if ((unsigned)ih < (unsigned)Hh) {
            size_t rb = ((size_t)b * Hh + ih) * Ww;
            if ((unsigned)iw < (unsigned)Ww)       { cA = cin4[rb + iw];     xA = xin4[rb + iw]; }
            if ((unsigned)(iw + 1) < (unsigned)Ww) { cB = cin4[rb + iw + 1]; xB = xin4[rb + iw + 1]; }
        }
        sdE[0][ly][j] = (v2f){cA.x, xA.x * cA.x};
        sdE[1][ly][j] = (v2f){cA.y, xA.y * cA.y};
        sdE[2][ly][j] = (v2f){cA.z, xA.z * cA.z};
        sdE[3][ly][j] = (v2f){cA.w, xA.w * cA.w};
        sdO[0][ly][j] = (v2f){cB.x, xB.x * cB.x};
        sdO[1][ly][j] = (v2f){cB.y, xB.y * cB.y};
        sdO[2][ly][j] = (v2f){cB.z, xB.z * cB.z};
        sdO[3][ly][j] = (v2f){cB.w, xB.w * cB.w};
    }
    wsum4(s_w4, 100, tid, &s_sum);
    __syncthreads();

    v2f aA[4] = {}, aB[4] = {};
    #pragma unroll 1
    for (int ci = 0; ci < 4; ++ci) {
        #pragma unroll
        for (int kj = 0; kj < 5; ++kj) {
            const v2f* rE = &sdE[ci][ty + kj][tx];
            const v2f* rO = &sdO[ci][ty + kj][tx];
            v2f e0 = rE[0], o0 = rO[0], e1 = rE[1], o1 = rO[1], e2 = rE[2], o2 = rO[2];
            const v2f* wr = (const v2f*)&s_w4[ci * 25 + kj * 5];
            TAP2(wr[0], wr[1], e0, o0)
            TAP2(wr[2], wr[3], o0, e1)
            TAP2(wr[4], wr[5], e1, o1)
            TAP2(wr[6], wr[7], o1, e2)
            TAP2(wr[8], wr[9], e2, o2)
        }
    }

    const int oh = oh0 + ty, ow = ow0 + 2 * tx;
    float4 bias = s_bias, ssum = s_sum;
    float rs0 = rcpf(ssum.x), rs1 = rcpf(ssum.y),
          rs2 = rcpf(ssum.z), rs3 = rcpf(ssum.w);
    float4 xoA, coA, xoB, coB;
    NC_EPI(aA, xoA, coA)
    NC_EPI(aB, xoB, coB)
    const bool rowok = oh < Hh, colA = ow < Ww, colB = ow + 1 < Ww;
    if (rowok && colA) {
        size_t t = ((size_t)b * Hh + oh) * Ww + ow;
        xout4[t] = xoA; cout4[t] = coA;
        if (colB) { xout4[t + 1] = xoB; cout4[t + 1] = coB; }
    }
    if (POOL) {
        float4 cb = coA, xb = xoA;
        if (coB.x > cb.x) { cb.x = coB.x; xb.x = xoB.x; }
        if (coB.y > cb.y) { cb.y = coB.y; xb.y = xoB.y; }
        if (coB.z > cb.z) { cb.z = coB.z; xb.z = xoB.z; }
        if (coB.w > cb.w) { cb.w = coB.w; xb.w = xoB.w; }
        float4 cb2, xb2;
        cb2.x = __shfl_down(cb.x, 16); xb2.x = __shfl_down(xb.x, 16);
        cb2.y = __shfl_down(cb.y, 16); xb2.y = __shfl_down(xb.y, 16);
        cb2.z = __shfl_down(cb.z, 16); xb2.z = __shfl_down(xb.z, 16);
        cb2.w = __shfl_down(cb.w, 16); xb2.w = __shfl_down(xb.w, 16);
        if (!(ty & 1) && rowok && colA) {
            if (cb2.x > cb.x) { cb.x = cb2.x; xb.x = xb2.x; }
            if (cb2.y > cb.y) { cb.y = cb2.y; xb.y = xb2.y; }
            if (cb2.z > cb.z) { cb.z = cb2.z; xb.z = xb2.z; }
            if (cb2.w > cb.w) { cb.w = cb2.w; xb.w = xb2.w; }
            cb.x *= 0.25f; cb.y *= 0.25f; cb.z *= 0.25f; cb.w *= 0.25f;
            size_t tp = ((size_t)b * (Hh >> 1) + (oh >> 1)) * (Ww >> 1) + (ow >> 1);
            xo_p[tp] = xb; co_p[tp] = cb;
        }
    }
}

// ---------------------------------------------------------------------------
// 3x3 nconv over concat{direct 4ch (Hin,Win), nearest-2x-up 4ch (Hin/2,Win/2)}.
// Up staged at native half-res. 32x16 tile, 2 px/thread, parity LDS (direct).
// UP_FIRST: up occupies weight channels 0-3 (w6) else 4-7 (w4,w5).
// ---------------------------------------------------------------------------
template<bool UP_FIRST, int PAD>
__global__ __launch_bounds__(256) void nconv3cat(
    const float4* __restrict__ xd4, const float4* __restrict__ cd4,
    const float4* __restrict__ xu4, const float4* __restrict__ cu4,
    const float* __restrict__ wraw, const float* __restrict__ braw,
    float4* __restrict__ xout4, float4* __restrict__ cout4,
    int Hin, int Win)
{
    __shared__ v2f sdE[4][18][18], sdO[4][18][18];   // direct, parity cols
    __shared__ v2f sup[4][10][19];                   // up, native half-res
    __shared__ float4 s_w4[72];
    __shared__ float4 s_sum, s_bias;

    const int Hout = Hin - 2 + 2 * PAD, Wout = Win - 2 + 2 * PAD;
    const int Hu = Hin / 2, Wu = Win / 2;
    const int b = blockIdx.z;
    const int oh0 = blockIdx.y * 16, ow0 = blockIdx.x * 32;
    const int tx = threadIdx.x, ty = threadIdx.y, tid = ty * 16 + tx;

    if (tid < 72) {
        float4 w;
        w.x = softplusf(wraw[tid]);       w.y = softplusf(wraw[72 + tid]);
        w.z = softplusf(wraw[144 + tid]); w.w = softplusf(wraw[216 + tid]);
        s_w4[tid] = w;
    }
    if (tid == 0) s_bias = make_float4(braw[0], braw[1], braw[2], braw[3]);
    __syncthreads();

    const float4 z = make_float4(0.f, 0.f, 0.f, 0.f);
    for (int i = tid; i < 18 * 17; i += 256) {          // direct: 18 rows x 17 pairs
        int ly = i / 17, j = i - ly * 17;
        int ih = oh0 - PAD + ly, iw = ow0 - PAD + 2 * j;
        float4 cA = z, xA = z, cB = z, xB = z;
        if ((unsigned)ih < (unsigned)Hin) {
            size_t rb = ((size_t)b * Hin + ih) * Win;
            if ((unsigned)iw < (unsigned)Win)       { cA = cd4[rb + iw];     xA = xd4[rb + iw]; }
            if ((unsigned)(iw + 1) < (unsigned)Win) { cB = cd4[rb + iw + 1]; xB = xd4[rb + iw + 1]; }
        }
        sdE[0][ly][j] = (v2f){cA.x, xA.x * cA.x};
        sdE[1][ly][j] = (v2f){cA.y, xA.y * cA.y};
        sdE[2][ly][j] = (v2f){cA.z, xA.z * cA.z};
        sdE[3][ly][j] = (v2f){cA.w, xA.w * cA.w};
        sdO[0][ly][j] = (v2f){cB.x, xB.x * cB.x};
        sdO[1][ly][j] = (v2f){cB.y, xB.y * cB.y};
        sdO[2][ly][j] = (v2f){cB.z, xB.z * cB.z};
        sdO[3][ly][j] = (v2f){cB.w, xB.w * cB.w};
    }
    const int ru0 = (oh0 - PAD) >> 1, cu0 = (ow0 - PAD) >> 1;
    for (int i = tid; i < 10 * 18; i += 256) {          // up: 10 rows x 18 cols
        int r = i / 18, k = i - r * 18;
        int ur = ru0 + r, uc = cu0 + k;
        float4 cU = z, xU = z;
        if ((unsigned)ur < (unsigned)Hu && (unsigned)uc < (unsigned)Wu) {
            size_t t = ((size_t)b * Hu + ur) * Wu + uc;
            cU = cu4[t]; xU = xu4[t];
        }
        sup[0][r][k] = (v2f){cU.x, xU.x * cU.x};
        sup[1][r][k] = (v2f){cU.y, xU.y * cU.y};
        sup[2][r][k] = (v2f){cU.z, xU.z * cU.z};
        sup[3][r][k] = (v2f){cU.w, xU.w * cU.w};
    }
    wsum4(s_w4, 72, tid, &s_sum);
    __syncthreads();

    v2f aA[4] = {}, aB[4] = {};
    #pragma unroll 1
    for (int ci = 0; ci < 4; ++ci) {
        const int chD = UP_FIRST ? ci + 4 : ci;
        const int chU = UP_FIRST ? ci : ci + 4;
        #pragma unroll
        for (int kj = 0; kj < 3; ++kj) {
            const v2f* rE = &sdE[ci][ty + kj][tx];
            const v2f* rO = &sdO[ci][ty + kj][tx];
            v2f e0 = rE[0], o0 = rO[0], e1 = rE[1], o1 = rO[1];
            const v2f* wr = (const v2f*)&s_w4[chD * 9 + kj * 3];
            TAP2(wr[0], wr[1], e0, o0)
            TAP2(wr[2], wr[3], o0, e1)
            TAP2(wr[4], wr[5], e1, o1)
        }
        #pragma unroll
        for (int kj = 0; kj < 3; ++kj) {
            int lyu = (ty + kj + PAD) >> 1;
            const v2f* ru = &sup[ci][lyu][tx];
            v2f u0 = ru[0], u1 = ru[1];
            v2f q0, q1, q2, q3;
            if (PAD == 1) {
                v2f u2 = ru[2];
                q0 = u0; q1 = u1; q2 = u1; q3 = u2;   // idx = (m+1)>>1
            } else {
                q0 = u0; q1 = u0; q2 = u1; q3 = u1;   // idx = m>>1
            }
            const v2f* wr = (const v2f*)&s_w4[chU * 9 + kj * 3];
            TAP2(wr[0], wr[1], q0, q1)
            TAP2(wr[2], wr[3], q1, q2)
            TAP2(wr[4], wr[5], q2, q3)
        }
    }
    NC_STORE_PACKED(Hout, Wout)
}

// ---------------------------------------------------------------------------
// 3x3 nconv 4->4 pad=1 (w65) + fused 1x1 nconv 4->1 (w7): writes the scalar
// pre-pool plane z (478x638) only. x/c planes never hit memory.
// ---------------------------------------------------------------------------
__global__ __launch_bounds__(256) void nconv3p_w7(
    const float4* __restrict__ xin4, const float4* __restrict__ cin4,
    const float* __restrict__ wraw, const float* __restrict__ braw,
    const float* __restrict__ w7raw, const float* __restrict__ b7raw,
    float* __restrict__ zout,
    int Hh, int Ww)
{
    __shared__ v2f sdE[4][18][18], sdO[4][18][18];
    __shared__ float4 s_w4[36];
    __shared__ float4 s_sum, s_bias, s_w7;
    __shared__ float s_b7;
    const int b = blockIdx.z;
    const int oh0 = blockIdx.y * 16, ow0 = blockIdx.x * 32;
    const int tx = threadIdx.x, ty = threadIdx.y, tid = ty * 16 + tx;

    if (tid < 36) {
        float4 w;
        w.x = softplusf(wraw[tid]);      w.y = softplusf(wraw[36 + tid]);
        w.z = softplusf(wraw[72 + tid]); w.w = softplusf(wraw[108 + tid]);
        s_w4[tid] = w;
    }
    if (tid == 0) {
        s_bias = make_float4(braw[0], braw[1], braw[2], braw[3]);
        s_w7 = make_float4(softplusf(w7raw[0]), softplusf(w7raw[1]),
                           softplusf(w7raw[2]), softplusf(w7raw[3]));
        s_b7 = b7raw[0];
    }
    __syncthreads();

    const float4 z = make_float4(0.f, 0.f, 0.f, 0.f);
    for (int i = tid; i < 18 * 17; i += 256) {
        int ly = i / 17, j = i - ly * 17;
        int ih = oh0 - 1 + ly, iw = ow0 - 1 + 2 * j;
        float4 cA = z, xA = z, cB = z, xB = z;
        if ((unsigned)ih < (unsigned)Hh) {
            size_t rb = ((size_t)b * Hh + ih) * Ww;
            if ((unsigned)iw < (unsigned)Ww)       { cA = cin4[rb + iw];     xA = xin4[rb + iw]; }
            if ((unsigned)(iw + 1) < (unsigned)Ww) { cB = cin4[rb + iw + 1]; xB = xin4[rb + iw + 1]; }
        }
        sdE[0][ly][j] = (v2f){cA.x, xA.x * cA.x};
        sdE[1][ly][j] = (v2f){cA.y, xA.y * cA.y};
        sdE[2][ly][j] = (v2f){cA.z, xA.z * cA.z};
        sdE[3][ly][j] = (v2f){cA.w, xA.w * cA.w};
        sdO[0][ly][j] = (v2f){cB.x, xB.x * cB.x};
        sdO[1][ly][j] = (v2f){cB.y, xB.y * cB.y};
        sdO[2][ly][j] = (v2f){cB.z, xB.z * cB.z};
        sdO[3][ly][j] = (v2f){cB.w, xB.w * cB.w};
    }
    wsum4(s_w4, 36, tid, &s_sum);
    __syncthreads();

    v2f aA[4] = {}, aB[4] = {};
    #pragma unroll 1
    for (int ci = 0; ci < 4; ++ci) {
        #pragma unroll
        for (int kj = 0; kj < 3; ++kj) {
            const v2f* rE = &sdE[ci][ty + kj][tx];
            const v2f* rO = &sdO[ci][ty + kj][tx];
            v2f e0 = rE[0], o0 = rO[0], e1 = rE[1], o1 = rO[1];
            const v2f* wr = (const v2f*)&s_w4[ci * 9 + kj * 3];
            TAP2(wr[0], wr[1], e0, o0)
            TAP2(wr[2], wr[3], o0, e1)
            TAP2(wr[4], wr[5], e1, o1)
        }
    }

    const int oh = oh0 + ty, ow = ow0 + 2 * tx;
    if (oh >= Hh || ow >= Ww) return;
    float4 bias = s_bias, ssum = s_sum, w7 = s_w7;
    float b7 = s_b7;
    float rs0 = rcpf(ssum.x), rs1 = rcpf(ssum.y),
          rs2 = rcpf(ssum.z), rs3 = rcpf(ssum.w);
    float4 xo, co;
    NC_EPI(aA, xo, co)
    float den7 = w7.x * co.x + w7.y * co.y + w7.z * co.z + w7.w * co.w;
    float nom7 = w7.x * xo.x * co.x + w7.y * xo.y * co.y
               + w7.z * xo.z * co.z + w7.w * xo.w * co.w;
    float zA = nom7 * rcpf(den7 + EPSN) + b7;
    size_t t = ((size_t)b * Hh + oh) * Ww + ow;
    if (ow + 1 < Ww) {
        NC_EPI(aB, xo, co)
        den7 = w7.x * co.x + w7.y * co.y + w7.z * co.z + w7.w * co.w;
        nom7 = w7.x * xo.x * co.x + w7.y * xo.y * co.y
             + w7.z * xo.z * co.z + w7.w * xo.w * co.w;
        float zB = nom7 * rcpf(den7 + EPSN) + b7;
        *(float2*)&zout[t] = make_float2(zA, zB);
    } else {
        zout[t] = zA;
    }
}

// ---------------------------------------------------------------------------
// Adaptive average pool (478,638) -> (480,640), windows of 1-2 per dim.
// ---------------------------------------------------------------------------
__global__ __launch_bounds__(256) void apoolk(
    const float* __restrict__ in, float* __restrict__ out)
{
    const int HI = 478, WI = 638, HO = 480, WO = 640;
    int total = 8 * HO * WO;
    int i = blockIdx.x * 256 + threadIdx.x;
    if (i >= total) return;
    int ow = i % WO;
    int oh = (i / WO) % HO;
    int b  = i / (WO * HO);
    int sh = (oh * HI) / HO, eh = ((oh + 1) * HI + HO - 1) / HO;
    int sw = (ow * WI) / WO, ew = ((ow + 1) * WI + WO - 1) / WO;
    float s = 0.f;
    for (int ih = sh; ih < eh; ++ih)
        for (int iw = sw; iw < ew; ++iw)
            s += in[((size_t)b * HI + ih) * WI + iw];
    out[i] = s * rcpf((float)((eh - sh) * (ew - sw)));
}

// ---------------------------------------------------------------------------
extern "C" void kernel_launch(void* const* d_in, const int* in_sizes, int n_in,
                              void* d_out, int out_size, void* d_ws, size_t ws_size,
                              hipStream_t stream)
{
    const float* S   = (const float*)d_in[1];
    const float* w1  = (const float*)d_in[3];  const float* b1  = (const float*)d_in[4];
    const float* w2  = (const float*)d_in[5];  const float* b2  = (const float*)d_in[6];
    const float* w3  = (const float*)d_in[7];  const float* b3  = (const float*)d_in[8];
    const float* w4  = (const float*)d_in[9];  const float* b4  = (const float*)d_in[10];
    const float* w5  = (const float*)d_in[11]; const float* b5  = (const float*)d_in[12];
    const float* w6  = (const float*)d_in[13]; const float* b6  = (const float*)d_in[14];
    const float* w65 = (const float*)d_in[15]; const float* b65 = (const float*)d_in[16];
    const float* w7  = (const float*)d_in[17]; const float* b7  = (const float*)d_in[18];
    float* out = (float*)d_out;
    float* ws  = (float*)d_ws;

    const size_t FULL = 9830400, HALF = 2457600, QUAR = 614400, EIGH = 153600;
    float4 *A0 = (float4*)ws,              *A1 = (float4*)(ws + FULL),
           *A2 = (float4*)(ws + 2*FULL),   *A3 = (float4*)(ws + 3*FULL);
    float4 *P0 = (float4*)(ws + 4*FULL),            *P1 = (float4*)(ws + 4*FULL + HALF),
           *P2 = (float4*)(ws + 4*FULL + 2*HALF),   *P3 = (float4*)(ws + 4*FULL + 3*HALF);
    float4 *Q0 = (float4*)(ws + 4*FULL + 4*HALF),          *Q1 = (float4*)(ws + 4*FULL + 4*HALF + QUAR),
           *Q2 = (float4*)(ws + 4*FULL + 4*HALF + 2*QUAR), *Q3 = (float4*)(ws + 4*FULL + 4*HALF + 3*QUAR);
    float4 *E0 = (float4*)(ws + 4*FULL + 4*HALF + 4*QUAR),
           *E1 = (float4*)(ws + 4*FULL + 4*HALF + 4*QUAR + EIGH),
           *E2 = (float4*)(ws + 4*FULL + 4*HALF + 4*QUAR + 2*EIGH),
           *E3 = (float4*)(ws + 4*FULL + 4*HALF + 4*QUAR + 3*EIGH);

    dim3 blk(16, 16);
    auto grd = [](int Ho, int Wo) { return dim3((Wo + 31) / 32, (Ho + 15) / 16, 8); };

    // encoder, full res
    nconv5_first<<<grd(480, 640), blk, 0, stream>>>(S, w1, b1, A0, A1, 480, 640);
    nconv5p4<false><<<grd(480, 640), blk, 0, stream>>>(A0, A1, w2, b2, A2, A3, nullptr, nullptr, 480, 640);
    nconv5p4<true ><<<grd(480, 640), blk, 0, stream>>>(A2, A3, w3, b3, A0, A1, P0, P1, 480, 640);  // x1,c1 + pooled
    // 1/2 scale
    nconv5p4<false><<<grd(240, 320), blk, 0, stream>>>(P0, P1, w2, b2, P2, P3, nullptr, nullptr, 240, 320);
    nconv5p4<true ><<<grd(240, 320), blk, 0, stream>>>(P2, P3, w3, b3, P0, P1, Q0, Q1, 240, 320);  // x2_ds + pooled
    // 1/4 scale
    nconv5p4<true ><<<grd(120, 160), blk, 0, stream>>>(Q0, Q1, w2, b2, Q2, Q3, E0, E1, 120, 160);  // x3_ds + pooled
    // 1/8 scale
    nconv5p4<false><<<grd(60, 80), blk, 0, stream>>>(E0, E1, w2, b2, E2, E3, nullptr, nullptr, 60, 80);  // x4_ds
    // decoder
    nconv3cat<false, 1><<<grd(120, 160), blk, 0, stream>>>(Q2, Q3, E2, E3, w4, b4, Q0, Q1, 120, 160);
    nconv3cat<false, 1><<<grd(240, 320), blk, 0, stream>>>(P0, P1, Q0, Q1, w5, b5, P2, P3, 240, 320);
    nconv3cat<true , 0><<<grd(478, 638), blk, 0, stream>>>(A0, A1, P2, P3, w6, b6, A2, A3, 480, 640);
    // w65 + w7 fused: writes scalar pre-pool plane into A0 region
    nconv3p_w7<<<grd(478, 638), blk, 0, stream>>>(A2, A3, w65, b65, w7, b7, (float*)A0, 478, 638);
    apoolk<<<(8 * 480 * 640 + 255) / 256, 256, 0, stream>>>((float*)A0, out);
}